// Round 4
// baseline (131.973 us; speedup 1.0000x reference)
//
#include <hip/hip_runtime.h>
#include <hip/hip_bf16.h>
#include <stdint.h>

// Chamfer loss: dist = ||x||^2 + ||y||^2 - 2 x.y via bf16 hi/lo-split MFMA.
// X pre-scaled by -2 (exact); acc initialized with x^2+y^2 so the accumulator
// IS the distance; epilogue = pure min reductions + device atomicMin + fused
// last-block finalize.
// R4: counted-vmcnt ring pipeline. BK=32, 8 K-tiles, ring of 4 LDS slots
// (tile k -> slot k&3). While computing tile k we stage tile k+2 (slot safe:
// last read at tile k-2). One raw s_barrier per tile; s_waitcnt vmcnt(4) at
// boundaries (tile k+2's 4 loads stay in flight across the barrier) - never
// vmcnt(0) in steady state. 64B-row swizzle: slot ^= (row>>1)&3 (2-way = free).

typedef __bf16  bf16x8 __attribute__((ext_vector_type(8)));
typedef float   f32x4  __attribute__((ext_vector_type(4)));

#define NPTS 8192
#define DIM  128
#define KC   256   // hi (0..127) | lo (128..255)
#define BK   32    // bf16 K per ring tile
#define NT   8     // K-tiles

__device__ __forceinline__ void gload_lds16(const void* gsrc, void* ldst) {
  __builtin_amdgcn_global_load_lds(
      (const __attribute__((address_space(1))) uint32_t*)(uintptr_t)gsrc,
      (__attribute__((address_space(3))) uint32_t*)(uintptr_t)ldst,
      16, 0, 0);
}

// ---------------------------------------------------------------- prep ----
__global__ __launch_bounds__(256) void prep_kernel(
    const float* __restrict__ x, const float* __restrict__ y,
    unsigned short* __restrict__ Xc, unsigned short* __restrict__ Yc,
    float* __restrict__ x2, float* __restrict__ y2,
    unsigned int* __restrict__ minx, unsigned int* __restrict__ miny,
    unsigned int* __restrict__ cnt)
{
  const int gt  = blockIdx.x * 256 + threadIdx.x;   // 0 .. 524287
  const int row = gt >> 5;                          // 0 .. 16383
  const int seg = gt & 31;                          // float4 slot in row
  const bool isx = row < NPTS;
  const float* src        = isx ? (x  + (size_t)row * DIM) : (y  + (size_t)(row - NPTS) * DIM);
  unsigned short* dst     = isx ? (Xc + (size_t)row * KC)  : (Yc + (size_t)(row - NPTS) * KC);

  f32x4 v = *reinterpret_cast<const f32x4*>(src + seg * 4);
  float sq = v[0]*v[0] + v[1]*v[1] + v[2]*v[2] + v[3]*v[3];
  #pragma unroll
  for (int m = 1; m <= 16; m <<= 1) sq += __shfl_xor(sq, m);   // 32-lane segmented reduce
  if (seg == 0) { if (isx) x2[row] = sq; else y2[row - NPTS] = sq; }

  const float scale = isx ? -2.0f : 1.0f;           // fold the -2 into X (exact)
  unsigned short hb[4], lb[4];
  #pragma unroll
  for (int i = 0; i < 4; ++i) {
    float f = scale * v[i];
    __hip_bfloat16 h = __float2bfloat16(f);
    float hf = __bfloat162float(h);
    __hip_bfloat16 l = __float2bfloat16(f - hf);
    hb[i] = __builtin_bit_cast(unsigned short, h);
    lb[i] = __builtin_bit_cast(unsigned short, l);
  }
  *reinterpret_cast<ushort4*>(dst + seg * 4)       = make_ushort4(hb[0], hb[1], hb[2], hb[3]);
  *reinterpret_cast<ushort4*>(dst + 128 + seg * 4) = make_ushort4(lb[0], lb[1], lb[2], lb[3]);

  if (gt < NPTS)          minx[gt]        = 0x7F800000u;   // +inf
  else if (gt < 2 * NPTS) miny[gt - NPTS] = 0x7F800000u;
  if (gt == 0) cnt[0] = 0u;
}

// ---------------------------------------------------------------- gemm ----
__global__ __launch_bounds__(512, 2) void chamfer_gemm(
    const unsigned short* __restrict__ Xc, const unsigned short* __restrict__ Yc,
    const float* __restrict__ x2, const float* __restrict__ y2,
    unsigned int* __restrict__ minx, unsigned int* __restrict__ miny,
    unsigned int* __restrict__ cnt, float* __restrict__ out)
{
  // ring of 4 slots; slot = 256 rows x 32 K bf16 = 16 KB per matrix
  __shared__ alignas(16) unsigned short As[4][8192];   // 64 KB
  __shared__ alignas(16) unsigned short Bs[4][8192];   // 64 KB
  __shared__ float colminLDS[2 * 256];
  __shared__ float rowminLDS[4 * 256];
  __shared__ float redLDS[8];
  __shared__ unsigned int lastFlag;

  const int tid  = threadIdx.x;
  const int lane = tid & 63;
  const int w    = tid >> 6;        // 0..7
  const int wr   = w >> 2;          // 0..1  (rows: wr*128)
  const int wc   = w & 3;           // 0..3  (cols: wc*64)

  // XCD swizzle (round-2 proven): 32x32 tile grid
  const int bid   = blockIdx.x;
  const int xcd   = bid & 7;
  const int local = bid >> 3;              // 0..127
  const int bi    = xcd * 4 + ((local >> 3) & 3);
  const int bj    = ((local >> 5) << 3) + (local & 7);

  // ---- staging geometry: chunk = 128 rows x 32 K = 8 KB = 512 thr x 16 B.
  // LDS linear: byte t*16 -> row_in_chunk = t>>2, slot4 = t&3.
  // Read layout wants LDS (row, s) to hold K-octet s ^ ((row>>1)&3)
  // -> pre-swizzle the global source octet.
  const int r128 = tid >> 2;                          // 0..127
  const int kgrp = (tid & 3) ^ ((tid >> 3) & 3);      // source K-octet
  const unsigned short* Asrc0 = Xc + (size_t)(bi * 256 +       r128) * KC + kgrp * 8;
  const unsigned short* Asrc1 = Xc + (size_t)(bi * 256 + 128 + r128) * KC + kgrp * 8;
  const unsigned short* Bsrc0 = Yc + (size_t)(bj * 256 +       r128) * KC + kgrp * 8;
  const unsigned short* Bsrc1 = Yc + (size_t)(bj * 256 + 128 + r128) * KC + kgrp * 8;
  const int wofs = w * 1024;                          // wave-uniform LDS base

  // ---- per-lane ds_read offsets (hoisted; slot base added per tile) ----
  const int l15 = lane & 15, q = lane >> 4;
  int aoff[8], boff[4];
  #pragma unroll
  for (int mi = 0; mi < 8; ++mi) {
    const int r = wr * 128 + mi * 16 + l15;
    aoff[mi] = r * 64 + ((q ^ ((r >> 1) & 3)) << 4);
  }
  #pragma unroll
  for (int ni = 0; ni < 4; ++ni) {
    const int c = wc * 64 + ni * 16 + l15;
    boff[ni] = c * 64 + ((q ^ ((c >> 1) & 3)) << 4);
  }

  // ---- acc init = x2[row] + y2[col]: accumulator IS the distance ----
  f32x4 acc[8][4];
  {
    f32x4 xv[8]; float yv[4];
    #pragma unroll
    for (int mi = 0; mi < 8; ++mi)
      xv[mi] = *reinterpret_cast<const f32x4*>(x2 + bi * 256 + wr * 128 + mi * 16 + ((lane >> 4) << 2));
    #pragma unroll
    for (int ni = 0; ni < 4; ++ni)
      yv[ni] = y2[bj * 256 + wc * 64 + ni * 16 + (lane & 15)];
    #pragma unroll
    for (int mi = 0; mi < 8; ++mi)
      #pragma unroll
      for (int ni = 0; ni < 4; ++ni)
        #pragma unroll
        for (int r = 0; r < 4; ++r)
          acc[mi][ni][r] = xv[mi][r] + yv[ni];
  }
  // drain acc-init loads so the counted vmcnt below sees only staging loads
  asm volatile("s_waitcnt vmcnt(0)" ::: "memory");

  // ---- prologue: stage tiles 0 and 1 (issue order matters for vmcnt) ----
  #pragma unroll
  for (int k = 0; k < 2; ++k) {
    gload_lds16(Asrc0 + k * BK, (char*)&As[k][0] + wofs);
    gload_lds16(Asrc1 + k * BK, (char*)&As[k][0] + 8192 + wofs);
    gload_lds16(Bsrc0 + k * BK, (char*)&Bs[k][0] + wofs);
    gload_lds16(Bsrc1 + k * BK, (char*)&Bs[k][0] + 8192 + wofs);
  }
  asm volatile("s_waitcnt vmcnt(4)" ::: "memory");    // tile 0 landed; tile 1 flying
  __builtin_amdgcn_s_barrier();

  // ---- main loop: 8 K-tiles, 2 phases each, counted vmcnt at boundaries ----
  #pragma unroll
  for (int k = 0; k < NT; ++k) {
    const char* Ab = (const char*)&As[k & 3][0];
    const char* Bb = (const char*)&Bs[k & 3][0];

    // phase A: B-frags + A mi0-3; stage A-chunks of tile k+2
    bf16x8 bfr[4], afr[4];
    #pragma unroll
    for (int ni = 0; ni < 4; ++ni)
      bfr[ni] = *reinterpret_cast<const bf16x8*>(Bb + boff[ni]);
    #pragma unroll
    for (int mi = 0; mi < 4; ++mi)
      afr[mi] = *reinterpret_cast<const bf16x8*>(Ab + aoff[mi]);
    if (k < NT - 2) {
      gload_lds16(Asrc0 + (k + 2) * BK, (char*)&As[(k + 2) & 3][0] + wofs);
      gload_lds16(Asrc1 + (k + 2) * BK, (char*)&As[(k + 2) & 3][0] + 8192 + wofs);
    }
    __builtin_amdgcn_s_setprio(1);
    #pragma unroll
    for (int mi = 0; mi < 4; ++mi)
      #pragma unroll
      for (int ni = 0; ni < 4; ++ni)
        acc[mi][ni] = __builtin_amdgcn_mfma_f32_16x16x32_bf16(afr[mi], bfr[ni], acc[mi][ni], 0, 0, 0);
    __builtin_amdgcn_s_setprio(0);

    // phase B: A mi4-7; stage B-chunks of tile k+2
    bf16x8 afr2[4];
    #pragma unroll
    for (int mi = 0; mi < 4; ++mi)
      afr2[mi] = *reinterpret_cast<const bf16x8*>(Ab + aoff[4 + mi]);
    if (k < NT - 2) {
      gload_lds16(Bsrc0 + (k + 2) * BK, (char*)&Bs[(k + 2) & 3][0] + wofs);
      gload_lds16(Bsrc1 + (k + 2) * BK, (char*)&Bs[(k + 2) & 3][0] + 8192 + wofs);
    }
    __builtin_amdgcn_s_setprio(1);
    #pragma unroll
    for (int mi = 0; mi < 4; ++mi)
      #pragma unroll
      for (int ni = 0; ni < 4; ++ni)
        acc[4 + mi][ni] = __builtin_amdgcn_mfma_f32_16x16x32_bf16(afr2[mi], bfr[ni], acc[4 + mi][ni], 0, 0, 0);
    __builtin_amdgcn_s_setprio(0);

    // tile boundary: tile k+1 must be landed for next iter; tile k+2 stays in flight
    if (k < NT - 1) {
      if (k < NT - 2) asm volatile("s_waitcnt vmcnt(4)" ::: "memory");
      else            asm volatile("s_waitcnt vmcnt(0)" ::: "memory");
      __builtin_amdgcn_s_barrier();
    }
  }

  // ---- epilogue: pure min reductions (acc already = dist, pre-clamp) ----
  float cm[4];
  #pragma unroll
  for (int ni = 0; ni < 4; ++ni) {
    float m = 3.0e38f;
    #pragma unroll
    for (int mi = 0; mi < 8; ++mi)
      #pragma unroll
      for (int r = 0; r < 4; ++r)
        m = fminf(m, acc[mi][ni][r]);
    cm[ni] = m;
  }
  {
    const bool hb0 = (lane & 16) != 0;
    float s0 = hb0 ? cm[0] : cm[2];
    float s1 = hb0 ? cm[1] : cm[3];
    float r0 = __shfl_xor(s0, 16);
    float r1 = __shfl_xor(s1, 16);
    float t0 = fminf(hb0 ? cm[2] : cm[0], r0);
    float t1 = fminf(hb0 ? cm[3] : cm[1], r1);
    const bool hb1 = (lane & 32) != 0;
    float s  = hb1 ? t0 : t1;
    float rr = __shfl_xor(s, 32);
    float cfin = fminf(hb1 ? t1 : t0, rr);
    const int ni = (hb0 ? 2 : 0) + (hb1 ? 1 : 0);    // bitrev2(lane>>4)
    colminLDS[wr * 256 + wc * 64 + ni * 16 + (lane & 15)] = cfin;
  }

  float rm[32];
  #pragma unroll
  for (int mi = 0; mi < 8; ++mi)
    #pragma unroll
    for (int r = 0; r < 4; ++r)
      rm[mi * 4 + r] = fminf(fminf(acc[mi][0][r], acc[mi][1][r]),
                             fminf(acc[mi][2][r], acc[mi][3][r]));
  #pragma unroll
  for (int b2 = 0; b2 < 4; ++b2) {
    const int  half = 16 >> b2;
    const bool up   = (lane >> b2) & 1;
    #pragma unroll
    for (int i = 0; i < half; ++i) {
      float snd = up ? rm[i] : rm[i + half];
      float rcv = __shfl_xor(snd, 1 << b2);
      rm[i] = fminf(up ? rm[i + half] : rm[i], rcv);
    }
  }
  {
    // surviving rm[e], e in {0,1}: idx = l0<<4 | l1<<3 | l2<<2 | l3<<1 | e
    const int base = ((lane & 1) << 4) | ((lane & 2) << 2) | (lane & 4) | ((lane & 8) >> 2);
    #pragma unroll
    for (int e = 0; e < 2; ++e) {
      const int idx = base | e;
      const int row_local = wr * 128 + (idx >> 2) * 16 + ((lane >> 4) << 2) + (idx & 3);
      rowminLDS[wc * 256 + row_local] = rm[e];
    }
  }
  __syncthreads();

  // combine waves, clamp at 0 (commutes with min), one atomic per row/col
  if (tid < 256) {
    float c = fminf(colminLDS[tid], colminLDS[256 + tid]);
    atomicMin(&miny[bj * 256 + tid], __float_as_uint(fmaxf(c, 0.f)));
  } else {
    const int r = tid - 256;
    float v = fminf(fminf(rowminLDS[r], rowminLDS[256 + r]),
                    fminf(rowminLDS[512 + r], rowminLDS[768 + r]));
    atomicMin(&minx[bi * 256 + r], __float_as_uint(fmaxf(v, 0.f)));
  }

  // ---- fused finalize: last block sums the min arrays ----
  __syncthreads();
  if (tid == 0) {
    __threadfence();
    unsigned int old = __hip_atomic_fetch_add(cnt, 1u, __ATOMIC_ACQ_REL, __HIP_MEMORY_SCOPE_AGENT);
    lastFlag = (old == 1023u) ? 1u : 0u;
  }
  __syncthreads();
  if (lastFlag) {
    float s = 0.f;
    for (int i = tid; i < NPTS; i += 512) {
      s += __uint_as_float(__hip_atomic_load(&minx[i], __ATOMIC_RELAXED, __HIP_MEMORY_SCOPE_AGENT));
      s += __uint_as_float(__hip_atomic_load(&miny[i], __ATOMIC_RELAXED, __HIP_MEMORY_SCOPE_AGENT));
    }
    #pragma unroll
    for (int m = 32; m >= 1; m >>= 1) s += __shfl_xor(s, m);
    if (lane == 0) redLDS[w] = s;
    __syncthreads();
    if (tid == 0) {
      float tsum = 0.f;
      #pragma unroll
      for (int i = 0; i < 8; ++i) tsum += redLDS[i];
      out[0] = tsum * (1.0f / (float)NPTS);
    }
  }
}

// ---------------------------------------------------------------- launch ----
extern "C" void kernel_launch(void* const* d_in, const int* in_sizes, int n_in,
                              void* d_out, int out_size, void* d_ws, size_t ws_size,
                              hipStream_t stream) {
  (void)in_sizes; (void)n_in; (void)out_size; (void)ws_size;
  const float* x = (const float*)d_in[0];
  const float* y = (const float*)d_in[1];
  char* ws = (char*)d_ws;

  // ws layout: Xc 4MB | Yc 4MB | x2 32KB | y2 32KB | minx 32KB | miny 32KB | cnt
  unsigned short* Xc  = (unsigned short*)(ws);
  unsigned short* Yc  = (unsigned short*)(ws + 4194304);
  float*          x2  = (float*)(ws + 8388608);
  float*          y2  = (float*)(ws + 8421376);
  unsigned int*   mnx = (unsigned int*)(ws + 8454144);
  unsigned int*   mny = (unsigned int*)(ws + 8486912);
  unsigned int*   cnt = (unsigned int*)(ws + 8519680);
  float*          out = (float*)d_out;

  prep_kernel<<<2048, 256, 0, stream>>>(x, y, Xc, Yc, x2, y2, mnx, mny, cnt);
  chamfer_gemm<<<1024, 512, 0, stream>>>(Xc, Yc, x2, y2, mnx, mny, cnt, out);
}

// Round 5
// 120.961 us; speedup vs baseline: 1.0910x; 1.0910x over previous
//
#include <hip/hip_runtime.h>
#include <hip/hip_bf16.h>
#include <stdint.h>

// Chamfer loss: dist = ||x||^2 + ||y||^2 - 2 x.y via PURE bf16 MFMA (K=128).
// (Round-4 finding: the prior K=256 hi/lo concat computed h.h + l.l -- the
// cross terms were never there, so it was numerically ~pure bf16 and passed
// with absmax 0.0; the l.l term is ~1e-5 relative. Drop it: half the MFMA.)
// X pre-scaled by -2 (exact); acc initialized with x2[i]+y2[j] so the
// accumulator IS the distance; epilogue = pure min reductions + atomicMin +
// fused last-block finalize.
// K=128 fits entirely in LDS: stage everything up front (16 global_load_lds
// per thread), ONE barrier, 128 MFMAs/wave with no in-loop sync at all.

typedef __bf16  bf16x8 __attribute__((ext_vector_type(8)));
typedef float   f32x4  __attribute__((ext_vector_type(4)));

#define NPTS 8192
#define DIM  128
#define KC   128   // bf16 K (pure hi)

__device__ __forceinline__ void gload_lds16(const void* gsrc, void* ldst) {
  __builtin_amdgcn_global_load_lds(
      (const __attribute__((address_space(1))) uint32_t*)(uintptr_t)gsrc,
      (__attribute__((address_space(3))) uint32_t*)(uintptr_t)ldst,
      16, 0, 0);
}

// ---------------------------------------------------------------- prep ----
// One float4 per thread (32 threads/row). Row norms (fp32 of ORIGINAL data),
// bf16 cast of (-2x) for X / (y) for Y, min arrays -> +inf, cnt -> 0.
__global__ __launch_bounds__(256) void prep_kernel(
    const float* __restrict__ x, const float* __restrict__ y,
    unsigned short* __restrict__ Xc, unsigned short* __restrict__ Yc,
    float* __restrict__ x2, float* __restrict__ y2,
    unsigned int* __restrict__ minx, unsigned int* __restrict__ miny,
    unsigned int* __restrict__ cnt)
{
  const int gt  = blockIdx.x * 256 + threadIdx.x;   // 0 .. 524287
  const int row = gt >> 5;                          // 0 .. 16383
  const int seg = gt & 31;                          // float4 slot in row
  const bool isx = row < NPTS;
  const float* src        = isx ? (x  + (size_t)row * DIM) : (y  + (size_t)(row - NPTS) * DIM);
  unsigned short* dst     = isx ? (Xc + (size_t)row * KC)  : (Yc + (size_t)(row - NPTS) * KC);

  f32x4 v = *reinterpret_cast<const f32x4*>(src + seg * 4);
  float sq = v[0]*v[0] + v[1]*v[1] + v[2]*v[2] + v[3]*v[3];
  #pragma unroll
  for (int m = 1; m <= 16; m <<= 1) sq += __shfl_xor(sq, m);   // 32-lane segmented reduce
  if (seg == 0) { if (isx) x2[row] = sq; else y2[row - NPTS] = sq; }

  const float scale = isx ? -2.0f : 1.0f;           // fold the -2 into X (exact)
  unsigned short hb[4];
  #pragma unroll
  for (int i = 0; i < 4; ++i) {
    __hip_bfloat16 h = __float2bfloat16(scale * v[i]);
    hb[i] = __builtin_bit_cast(unsigned short, h);
  }
  *reinterpret_cast<ushort4*>(dst + seg * 4) = make_ushort4(hb[0], hb[1], hb[2], hb[3]);

  if (gt < NPTS)          minx[gt]        = 0x7F800000u;   // +inf
  else if (gt < 2 * NPTS) miny[gt - NPTS] = 0x7F800000u;
  if (gt == 0) cnt[0] = 0u;
}

// ---------------------------------------------------------------- gemm ----
// 256x256 tile, 512 threads / 8 waves (2x4); per wave 128x64 via acc[8][4]
// of mfma_f32_16x16x32_bf16. Whole K=128 staged once: As/Bs[kt] = K-chunk kt.
__global__ __launch_bounds__(512, 2) void chamfer_gemm(
    const unsigned short* __restrict__ Xc, const unsigned short* __restrict__ Yc,
    const float* __restrict__ x2, const float* __restrict__ y2,
    unsigned int* __restrict__ minx, unsigned int* __restrict__ miny,
    unsigned int* __restrict__ cnt, float* __restrict__ out)
{
  __shared__ alignas(16) unsigned short As[2][256 * 64];   // 32 KB each (K 0-63 | 64-127)
  __shared__ alignas(16) unsigned short Bs[2][256 * 64];
  // reduce scratch overlaid on As[0] (used only after the post-MFMA barrier)
  float* colminLDS = (float*)&As[0][0];          // [2][256]
  float* rowminLDS = (float*)&As[0][0] + 512;    // [4][256]
  __shared__ float redLDS[8];
  __shared__ unsigned int lastFlag;

  const int tid  = threadIdx.x;
  const int lane = tid & 63;
  const int w    = tid >> 6;        // 0..7
  const int wr   = w >> 2;          // 0..1  (rows: wr*128)
  const int wc   = w & 3;           // 0..3  (cols: wc*64)

  // XCD-chunked bijective swizzle (round-2 proven): 32x32 tile grid
  const int bid   = blockIdx.x;
  const int xcd   = bid & 7;
  const int local = bid >> 3;              // 0..127
  const int bi    = xcd * 4 + ((local >> 3) & 3);
  const int bj    = ((local >> 5) << 3) + (local & 7);

  // staging geometry (round-2 proven, KC now 128): LDS byte = row*128 + slot*16
  // (linear), slot = tid&7, row = l*64 + (tid>>3); source pre-swizzled:
  // kgroup = slot ^ (row&7).
  const int r64  = tid >> 3;               // 0..63
  const int kgrp = (tid & 7) ^ (r64 & 7);
  const unsigned short* Abase = Xc + (size_t)(bi * 256 + r64) * KC + kgrp * 8;
  const unsigned short* Bbase = Yc + (size_t)(bj * 256 + r64) * KC + kgrp * 8;

  // ---- stage the ENTIRE K=128 up front (16 loads/thread), no double-buffer
  #pragma unroll
  for (int kt = 0; kt < 2; ++kt) {
    const unsigned short* Asrc = Abase + kt * 64;
    const unsigned short* Bsrc = Bbase + kt * 64;
    char* Ad = (char*)&As[kt][0] + w * 1024;       // wave-uniform LDS base
    char* Bd = (char*)&Bs[kt][0] + w * 1024;
    #pragma unroll
    for (int l = 0; l < 4; ++l) {                  // 64 rows per round
      gload_lds16(Asrc + (size_t)l * 64 * KC, Ad + l * 8192);
      gload_lds16(Bsrc + (size_t)l * 64 * KC, Bd + l * 8192);
    }
  }

  // ---- acc init = x2[row] + y2[col] (latency overlaps the staging DMA) ----
  f32x4 acc[8][4];
  {
    f32x4 xv[8]; float yv[4];
    #pragma unroll
    for (int mi = 0; mi < 8; ++mi)
      xv[mi] = *reinterpret_cast<const f32x4*>(x2 + bi * 256 + wr * 128 + mi * 16 + ((lane >> 4) << 2));
    #pragma unroll
    for (int ni = 0; ni < 4; ++ni)
      yv[ni] = y2[bj * 256 + wc * 64 + ni * 16 + (lane & 15)];
    #pragma unroll
    for (int mi = 0; mi < 8; ++mi)
      #pragma unroll
      for (int ni = 0; ni < 4; ++ni)
        #pragma unroll
        for (int r = 0; r < 4; ++r)
          acc[mi][ni][r] = xv[mi][r] + yv[ni];
  }

  __syncthreads();   // drains vmcnt -> all of A,B staged; the ONLY pre-MFMA sync

  // ---- 128 MFMAs/wave, no barriers, no staging, nothing in between ----
  #pragma unroll
  for (int kt = 0; kt < 2; ++kt) {
    const char* Ab = (const char*)&As[kt][0];
    const char* Bb = (const char*)&Bs[kt][0];

    bf16x8 bfr[4][2];
    #pragma unroll
    for (int ni = 0; ni < 4; ++ni) {
      const int col = wc * 64 + ni * 16 + (lane & 15);
      const int swz = (col & 7) << 4;
      #pragma unroll
      for (int ks = 0; ks < 2; ++ks) {
        const int ofs = (ks * 64 + ((lane >> 4) << 4)) ^ swz;
        bfr[ni][ks] = *reinterpret_cast<const bf16x8*>(Bb + col * 128 + ofs);
      }
    }
    #pragma unroll
    for (int mi = 0; mi < 8; ++mi) {
      const int rowl = wr * 128 + mi * 16 + (lane & 15);
      const int swz  = (rowl & 7) << 4;
      const bf16x8 a0 = *reinterpret_cast<const bf16x8*>(Ab + rowl * 128 + ((  0 + ((lane >> 4) << 4)) ^ swz));
      const bf16x8 a1 = *reinterpret_cast<const bf16x8*>(Ab + rowl * 128 + (( 64 + ((lane >> 4) << 4)) ^ swz));
      #pragma unroll
      for (int ni = 0; ni < 4; ++ni) {
        acc[mi][ni] = __builtin_amdgcn_mfma_f32_16x16x32_bf16(a0, bfr[ni][0], acc[mi][ni], 0, 0, 0);
        acc[mi][ni] = __builtin_amdgcn_mfma_f32_16x16x32_bf16(a1, bfr[ni][1], acc[mi][ni], 0, 0, 0);
      }
    }
  }

  __syncthreads();   // all waves done reading As before scratch overlay

  // ---- epilogue: acc already holds dist (pre-clamp); pure min reductions ----
  float cm[4];
  #pragma unroll
  for (int ni = 0; ni < 4; ++ni) {
    float m = 3.0e38f;
    #pragma unroll
    for (int mi = 0; mi < 8; ++mi)
      #pragma unroll
      for (int r = 0; r < 4; ++r)
        m = fminf(m, acc[mi][ni][r]);
    cm[ni] = m;
  }
  {
    const bool hb0 = (lane & 16) != 0;
    float s0 = hb0 ? cm[0] : cm[2];
    float s1 = hb0 ? cm[1] : cm[3];
    float r0 = __shfl_xor(s0, 16);
    float r1 = __shfl_xor(s1, 16);
    float t0 = fminf(hb0 ? cm[2] : cm[0], r0);
    float t1 = fminf(hb0 ? cm[3] : cm[1], r1);
    const bool hb1 = (lane & 32) != 0;
    float s  = hb1 ? t0 : t1;
    float rr = __shfl_xor(s, 32);
    float cfin = fminf(hb1 ? t1 : t0, rr);
    const int ni = (hb0 ? 2 : 0) + (hb1 ? 1 : 0);    // bitrev2(lane>>4)
    colminLDS[wr * 256 + wc * 64 + ni * 16 + (lane & 15)] = cfin;
  }

  float rm[32];
  #pragma unroll
  for (int mi = 0; mi < 8; ++mi)
    #pragma unroll
    for (int r = 0; r < 4; ++r)
      rm[mi * 4 + r] = fminf(fminf(acc[mi][0][r], acc[mi][1][r]),
                             fminf(acc[mi][2][r], acc[mi][3][r]));
  #pragma unroll
  for (int b2 = 0; b2 < 4; ++b2) {
    const int  half = 16 >> b2;
    const bool up   = (lane >> b2) & 1;
    #pragma unroll
    for (int i = 0; i < half; ++i) {
      float snd = up ? rm[i] : rm[i + half];
      float rcv = __shfl_xor(snd, 1 << b2);
      rm[i] = fminf(up ? rm[i + half] : rm[i], rcv);
    }
  }
  {
    // surviving rm[e], e in {0,1}: idx = l0<<4 | l1<<3 | l2<<2 | l3<<1 | e
    const int base = ((lane & 1) << 4) | ((lane & 2) << 2) | (lane & 4) | ((lane & 8) >> 2);
    #pragma unroll
    for (int e = 0; e < 2; ++e) {
      const int idx = base | e;
      const int row_local = wr * 128 + (idx >> 2) * 16 + ((lane >> 4) << 2) + (idx & 3);
      rowminLDS[wc * 256 + row_local] = rm[e];
    }
  }
  __syncthreads();

  // combine waves, clamp at 0 (commutes with min), one atomic per row/col
  if (tid < 256) {
    float c = fminf(colminLDS[tid], colminLDS[256 + tid]);
    atomicMin(&miny[bj * 256 + tid], __float_as_uint(fmaxf(c, 0.f)));
  } else {
    const int r = tid - 256;
    float v = fminf(fminf(rowminLDS[r], rowminLDS[256 + r]),
                    fminf(rowminLDS[512 + r], rowminLDS[768 + r]));
    atomicMin(&minx[bi * 256 + r], __float_as_uint(fmaxf(v, 0.f)));
  }

  // ---- fused finalize: last block sums the min arrays ----
  __syncthreads();
  if (tid == 0) {
    __threadfence();
    unsigned int old = __hip_atomic_fetch_add(cnt, 1u, __ATOMIC_ACQ_REL, __HIP_MEMORY_SCOPE_AGENT);
    lastFlag = (old == 1023u) ? 1u : 0u;
  }
  __syncthreads();
  if (lastFlag) {
    float s = 0.f;
    for (int i = tid; i < NPTS; i += 512) {
      s += __uint_as_float(__hip_atomic_load(&minx[i], __ATOMIC_RELAXED, __HIP_MEMORY_SCOPE_AGENT));
      s += __uint_as_float(__hip_atomic_load(&miny[i], __ATOMIC_RELAXED, __HIP_MEMORY_SCOPE_AGENT));
    }
    #pragma unroll
    for (int m = 32; m >= 1; m >>= 1) s += __shfl_xor(s, m);
    if (lane == 0) redLDS[w] = s;
    __syncthreads();
    if (tid == 0) {
      float tsum = 0.f;
      #pragma unroll
      for (int i = 0; i < 8; ++i) tsum += redLDS[i];
      out[0] = tsum * (1.0f / (float)NPTS);
    }
  }
}

// ---------------------------------------------------------------- launch ----
extern "C" void kernel_launch(void* const* d_in, const int* in_sizes, int n_in,
                              void* d_out, int out_size, void* d_ws, size_t ws_size,
                              hipStream_t stream) {
  (void)in_sizes; (void)n_in; (void)out_size; (void)ws_size;
  const float* x = (const float*)d_in[0];
  const float* y = (const float*)d_in[1];
  char* ws = (char*)d_ws;

  // ws layout: Xc 2MB | Yc 2MB | x2 32KB | y2 32KB | minx 32KB | miny 32KB | cnt
  unsigned short* Xc  = (unsigned short*)(ws);
  unsigned short* Yc  = (unsigned short*)(ws + 2097152);
  float*          x2  = (float*)(ws + 4194304);
  float*          y2  = (float*)(ws + 4227072);
  unsigned int*   mnx = (unsigned int*)(ws + 4259840);
  unsigned int*   mny = (unsigned int*)(ws + 4292608);
  unsigned int*   cnt = (unsigned int*)(ws + 4325376);
  float*          out = (float*)d_out;

  prep_kernel<<<2048, 256, 0, stream>>>(x, y, Xc, Yc, x2, y2, mnx, mny, cnt);
  chamfer_gemm<<<1024, 512, 0, stream>>>(Xc, Yc, x2, y2, mnx, mny, cnt, out);
}

// Round 6
// 90.819 us; speedup vs baseline: 1.4531x; 1.3319x over previous
//
#include <hip/hip_runtime.h>
#include <hip/hip_bf16.h>
#include <stdint.h>

// Chamfer loss: dist = ||x||^2 + ||y||^2 - 2 x.y via pure bf16 MFMA, K=128.
// Round-2 structure VERBATIM (best measured per-FLOP: pipelined BK=64
// double-buffer, prefetch-before-compute, separate finalize kernel, 1024
// blocks + XCD swizzle) with exactly ONE change: K=256 hi/lo -> K=128 pure
// bf16 (round-4 analysis: the hi/lo concat had no cross terms, so it was
// numerically ~pure bf16 already and passed with absmax 0.0).
// X pre-scaled by -2 (exact); acc initialized with x2[i]+y2[j] so the
// accumulator IS the distance; epilogue = pure min reductions + atomicMin.

typedef __bf16  bf16x8 __attribute__((ext_vector_type(8)));
typedef float   f32x4  __attribute__((ext_vector_type(4)));

#define NPTS 8192
#define DIM  128
#define KC   128   // bf16 K (pure hi)

__device__ __forceinline__ void gload_lds16(const void* gsrc, void* ldst) {
  __builtin_amdgcn_global_load_lds(
      (const __attribute__((address_space(1))) uint32_t*)(uintptr_t)gsrc,
      (__attribute__((address_space(3))) uint32_t*)(uintptr_t)ldst,
      16, 0, 0);
}

// ---------------------------------------------------------------- prep ----
// One float4 per thread (32 threads/row). Row norms (fp32 of ORIGINAL data),
// bf16 cast of (-2x) for X / (y) for Y, min arrays -> +inf.
__global__ __launch_bounds__(256) void prep_kernel(
    const float* __restrict__ x, const float* __restrict__ y,
    unsigned short* __restrict__ Xc, unsigned short* __restrict__ Yc,
    float* __restrict__ x2, float* __restrict__ y2,
    unsigned int* __restrict__ minx, unsigned int* __restrict__ miny)
{
  const int gt  = blockIdx.x * 256 + threadIdx.x;   // 0 .. 524287
  const int row = gt >> 5;                          // 0 .. 16383
  const int seg = gt & 31;                          // float4 slot in row
  const bool isx = row < NPTS;
  const float* src        = isx ? (x  + (size_t)row * DIM) : (y  + (size_t)(row - NPTS) * DIM);
  unsigned short* dst     = isx ? (Xc + (size_t)row * KC)  : (Yc + (size_t)(row - NPTS) * KC);

  f32x4 v = *reinterpret_cast<const f32x4*>(src + seg * 4);
  float sq = v[0]*v[0] + v[1]*v[1] + v[2]*v[2] + v[3]*v[3];
  #pragma unroll
  for (int m = 1; m <= 16; m <<= 1) sq += __shfl_xor(sq, m);   // 32-lane segmented reduce
  if (seg == 0) { if (isx) x2[row] = sq; else y2[row - NPTS] = sq; }

  const float scale = isx ? -2.0f : 1.0f;           // fold the -2 into X (exact)
  unsigned short hb[4];
  #pragma unroll
  for (int i = 0; i < 4; ++i) {
    __hip_bfloat16 h = __float2bfloat16(scale * v[i]);
    hb[i] = __builtin_bit_cast(unsigned short, h);
  }
  *reinterpret_cast<ushort4*>(dst + seg * 4) = make_ushort4(hb[0], hb[1], hb[2], hb[3]);

  if (gt < NPTS)          minx[gt]        = 0x7F800000u;   // +inf
  else if (gt < 2 * NPTS) miny[gt - NPTS] = 0x7F800000u;
}

// ---------------------------------------------------------------- gemm ----
// 256x256 tile, 512 threads / 8 waves (2x4); per wave 128x64 via acc[8][4]
// of mfma_f32_16x16x32_bf16. K=128 in 2 chunks of 64, double-buffered:
// stage(0); sync; { stage(1) || compute(0); sync; compute(1); sync }.
__global__ __launch_bounds__(512, 2) void chamfer_gemm(
    const unsigned short* __restrict__ Xc, const unsigned short* __restrict__ Yc,
    const float* __restrict__ x2, const float* __restrict__ y2,
    unsigned int* __restrict__ minx, unsigned int* __restrict__ miny)
{
  __shared__ alignas(16) unsigned short As[2][256 * 64];   // 32 KB each
  __shared__ alignas(16) unsigned short Bs[2][256 * 64];
  // reduce scratch overlaid on As[0] (only touched after its last compute use)
  float* colminLDS = (float*)&As[0][0];          // [2][256]
  float* rowminLDS = (float*)&As[0][0] + 512;    // [4][256]

  const int tid  = threadIdx.x;
  const int lane = tid & 63;
  const int w    = tid >> 6;        // 0..7
  const int wr   = w >> 2;          // 0..1  (rows: wr*128)
  const int wc   = w & 3;           // 0..3  (cols: wc*64)

  // XCD-chunked bijective swizzle: XCD k owns bi in [4k,4k+4), bj sub-grouped by 8
  const int bid   = blockIdx.x;
  const int xcd   = bid & 7;
  const int local = bid >> 3;              // 0..127
  const int bi    = xcd * 4 + ((local >> 3) & 3);
  const int bj    = ((local >> 5) << 3) + (local & 7);

  // staging geometry: LDS byte = row*128 + slot*16 (linear), slot = tid&7,
  // row = l*64 + (tid>>3); source pre-swizzled: kgroup = slot ^ (row&7).
  const int r64  = tid >> 3;               // 0..63
  const int kgrp = (tid & 7) ^ (r64 & 7);
  const unsigned short* Abase = Xc + (size_t)(bi * 256 + r64) * KC + kgrp * 8;
  const unsigned short* Bbase = Yc + (size_t)(bj * 256 + r64) * KC + kgrp * 8;

  auto STAGE = [&](int buf, int kt) {
    const unsigned short* Asrc = Abase + kt * 64;
    const unsigned short* Bsrc = Bbase + kt * 64;
    char* Ad = (char*)&As[buf][0] + w * 1024;      // wave-uniform LDS base
    char* Bd = (char*)&Bs[buf][0] + w * 1024;
    #pragma unroll
    for (int l = 0; l < 4; ++l) {                  // 64 rows per round
      gload_lds16(Asrc + (size_t)l * 64 * KC, Ad + l * 8192);
      gload_lds16(Bsrc + (size_t)l * 64 * KC, Bd + l * 8192);
    }
  };

  // acc init = x2[row] + y2[col]  ->  accumulator IS the distance
  f32x4 acc[8][4];
  {
    f32x4 xv[8]; float yv[4];
    #pragma unroll
    for (int mi = 0; mi < 8; ++mi)
      xv[mi] = *reinterpret_cast<const f32x4*>(x2 + bi * 256 + wr * 128 + mi * 16 + ((lane >> 4) << 2));
    #pragma unroll
    for (int ni = 0; ni < 4; ++ni)
      yv[ni] = y2[bj * 256 + wc * 64 + ni * 16 + (lane & 15)];
    #pragma unroll
    for (int mi = 0; mi < 8; ++mi)
      #pragma unroll
      for (int ni = 0; ni < 4; ++ni)
        #pragma unroll
        for (int r = 0; r < 4; ++r)
          acc[mi][ni][r] = xv[mi][r] + yv[ni];
  }

  STAGE(0, 0);
  __syncthreads();   // drains vmcnt -> buf0 ready

  #pragma unroll
  for (int kt = 0; kt < 2; ++kt) {
    if (kt < 1) STAGE(1, 1);                       // prefetch overlaps compute(0)
    const char* Ab = (const char*)&As[kt][0];
    const char* Bb = (const char*)&Bs[kt][0];

    bf16x8 bfr[4][2];
    #pragma unroll
    for (int ni = 0; ni < 4; ++ni) {
      const int col = wc * 64 + ni * 16 + (lane & 15);
      const int swz = (col & 7) << 4;
      #pragma unroll
      for (int ks = 0; ks < 2; ++ks) {
        const int ofs = (ks * 64 + ((lane >> 4) << 4)) ^ swz;
        bfr[ni][ks] = *reinterpret_cast<const bf16x8*>(Bb + col * 128 + ofs);
      }
    }
    #pragma unroll
    for (int mi = 0; mi < 8; ++mi) {
      const int rowl = wr * 128 + mi * 16 + (lane & 15);
      const int swz  = (rowl & 7) << 4;
      const bf16x8 a0 = *reinterpret_cast<const bf16x8*>(Ab + rowl * 128 + ((  0 + ((lane >> 4) << 4)) ^ swz));
      const bf16x8 a1 = *reinterpret_cast<const bf16x8*>(Ab + rowl * 128 + (( 64 + ((lane >> 4) << 4)) ^ swz));
      #pragma unroll
      for (int ni = 0; ni < 4; ++ni) {
        acc[mi][ni] = __builtin_amdgcn_mfma_f32_16x16x32_bf16(a0, bfr[ni][0], acc[mi][ni], 0, 0, 0);
        acc[mi][ni] = __builtin_amdgcn_mfma_f32_16x16x32_bf16(a1, bfr[ni][1], acc[mi][ni], 0, 0, 0);
      }
    }
    __syncthreads();   // staged loads landed; compute done before buffer reuse
  }

  // ---- epilogue: acc already holds dist (pre-clamp); pure min reductions ----
  float cm[4];
  #pragma unroll
  for (int ni = 0; ni < 4; ++ni) {
    float m = 3.0e38f;
    #pragma unroll
    for (int mi = 0; mi < 8; ++mi)
      #pragma unroll
      for (int r = 0; r < 4; ++r)
        m = fminf(m, acc[mi][ni][r]);
    cm[ni] = m;
  }
  {
    const bool hb0 = (lane & 16) != 0;
    float s0 = hb0 ? cm[0] : cm[2];
    float s1 = hb0 ? cm[1] : cm[3];
    float r0 = __shfl_xor(s0, 16);
    float r1 = __shfl_xor(s1, 16);
    float t0 = fminf(hb0 ? cm[2] : cm[0], r0);
    float t1 = fminf(hb0 ? cm[3] : cm[1], r1);
    const bool hb1 = (lane & 32) != 0;
    float s  = hb1 ? t0 : t1;
    float rr = __shfl_xor(s, 32);
    float cfin = fminf(hb1 ? t1 : t0, rr);
    const int ni = (hb0 ? 2 : 0) + (hb1 ? 1 : 0);    // bitrev2(lane>>4)
    colminLDS[wr * 256 + wc * 64 + ni * 16 + (lane & 15)] = cfin;
  }

  float rm[32];
  #pragma unroll
  for (int mi = 0; mi < 8; ++mi)
    #pragma unroll
    for (int r = 0; r < 4; ++r)
      rm[mi * 4 + r] = fminf(fminf(acc[mi][0][r], acc[mi][1][r]),
                             fminf(acc[mi][2][r], acc[mi][3][r]));
  #pragma unroll
  for (int b2 = 0; b2 < 4; ++b2) {
    const int  half = 16 >> b2;
    const bool up   = (lane >> b2) & 1;
    #pragma unroll
    for (int i = 0; i < half; ++i) {
      float snd = up ? rm[i] : rm[i + half];
      float rcv = __shfl_xor(snd, 1 << b2);
      rm[i] = fminf(up ? rm[i + half] : rm[i], rcv);
    }
  }
  {
    // surviving rm[e], e in {0,1}: idx = l0<<4 | l1<<3 | l2<<2 | l3<<1 | e
    const int base = ((lane & 1) << 4) | ((lane & 2) << 2) | (lane & 4) | ((lane & 8) >> 2);
    #pragma unroll
    for (int e = 0; e < 2; ++e) {
      const int idx = base | e;
      const int row_local = wr * 128 + (idx >> 2) * 16 + ((lane >> 4) << 2) + (idx & 3);
      rowminLDS[wc * 256 + row_local] = rm[e];
    }
  }
  __syncthreads();

  // combine waves, clamp at 0 (commutes with min), one atomic per row/col
  if (tid < 256) {
    float c = fminf(colminLDS[tid], colminLDS[256 + tid]);
    atomicMin(&miny[bj * 256 + tid], __float_as_uint(fmaxf(c, 0.f)));
  } else {
    const int r = tid - 256;
    float v = fminf(fminf(rowminLDS[r], rowminLDS[256 + r]),
                    fminf(rowminLDS[512 + r], rowminLDS[768 + r]));
    atomicMin(&minx[bi * 256 + r], __float_as_uint(fmaxf(v, 0.f)));
  }
}

// ------------------------------------------------------------- finalize ----
__global__ __launch_bounds__(256) void finalize_kernel(
    const unsigned int* __restrict__ minx, const unsigned int* __restrict__ miny,
    float* __restrict__ out)
{
  // all stored patterns are non-negative floats; reinterpret directly
  const f32x4* mx = (const f32x4*)minx;
  const f32x4* my = (const f32x4*)miny;
  float s = 0.f;
  for (int i = threadIdx.x; i < NPTS / 4; i += 256) {
    f32x4 a = mx[i], b = my[i];
    s += (a[0] + a[1] + a[2] + a[3]) + (b[0] + b[1] + b[2] + b[3]);
  }
  #pragma unroll
  for (int m = 32; m >= 1; m >>= 1) s += __shfl_xor(s, m);
  __shared__ float partial[4];
  if ((threadIdx.x & 63) == 0) partial[threadIdx.x >> 6] = s;
  __syncthreads();
  if (threadIdx.x == 0)
    out[0] = (partial[0] + partial[1] + partial[2] + partial[3]) * (1.0f / (float)NPTS);
}

// ---------------------------------------------------------------- launch ----
extern "C" void kernel_launch(void* const* d_in, const int* in_sizes, int n_in,
                              void* d_out, int out_size, void* d_ws, size_t ws_size,
                              hipStream_t stream) {
  (void)in_sizes; (void)n_in; (void)out_size; (void)ws_size;
  const float* x = (const float*)d_in[0];
  const float* y = (const float*)d_in[1];
  char* ws = (char*)d_ws;

  // ws layout: Xc 2MB | Yc 2MB | x2 32KB | y2 32KB | minx 32KB | miny 32KB
  unsigned short* Xc  = (unsigned short*)(ws);
  unsigned short* Yc  = (unsigned short*)(ws + 2097152);
  float*          x2  = (float*)(ws + 4194304);
  float*          y2  = (float*)(ws + 4227072);
  unsigned int*   mnx = (unsigned int*)(ws + 4259840);
  unsigned int*   mny = (unsigned int*)(ws + 4292608);
  float*          out = (float*)d_out;

  prep_kernel<<<2048, 256, 0, stream>>>(x, y, Xc, Yc, x2, y2, mnx, mny);
  chamfer_gemm<<<1024, 512, 0, stream>>>(Xc, Yc, x2, y2, mnx, mny);
  finalize_kernel<<<1, 256, 0, stream>>>(mnx, mny, out);
}

// Round 7
// 86.052 us; speedup vs baseline: 1.5336x; 1.0554x over previous
//
#include <hip/hip_runtime.h>
#include <hip/hip_bf16.h>
#include <stdint.h>

// Chamfer loss: dist = ||x||^2 + ||y||^2 - 2 x.y via pure bf16 MFMA, K=128.
// R7: A-panel hoisting. Grid 256 blocks (1/CU), each block owns 4 tiles
// (same bi, bj0..bj0+3). A (256 rows x K=128, 64 KB) staged ONCE and kept
// resident in LDS; B double-buffers 2x32 KB across the 4 tiles (8 compute
// phases). Same proven inner mechanics as R6 (stage geometry, pre-swizzled
// source + XOR ds_read swizzle, fragment layout, min-fold epilogue), same
// __syncthreads-only skeleton. minx accumulated in registers across tiles
// (one atomic per row at the end); y^2 prefetched one tile ahead.
// XCD map: xcd=b&7 owns bi in [4*xcd, 4*xcd+4) x all bj -> 2.25 MB L2 set.

typedef __bf16  bf16x8 __attribute__((ext_vector_type(8)));
typedef float   f32x4  __attribute__((ext_vector_type(4)));

#define NPTS 8192
#define DIM  128
#define KC   128   // bf16 K (pure hi)

__device__ __forceinline__ void gload_lds16(const void* gsrc, void* ldst) {
  __builtin_amdgcn_global_load_lds(
      (const __attribute__((address_space(1))) uint32_t*)(uintptr_t)gsrc,
      (__attribute__((address_space(3))) uint32_t*)(uintptr_t)ldst,
      16, 0, 0);
}

// ---------------------------------------------------------------- prep ----
// One float4 per thread (32 threads/row). Row norms (fp32 of ORIGINAL data),
// bf16 cast of (-2x) for X / (y) for Y, min arrays -> +inf.
__global__ __launch_bounds__(256) void prep_kernel(
    const float* __restrict__ x, const float* __restrict__ y,
    unsigned short* __restrict__ Xc, unsigned short* __restrict__ Yc,
    float* __restrict__ x2, float* __restrict__ y2,
    unsigned int* __restrict__ minx, unsigned int* __restrict__ miny)
{
  const int gt  = blockIdx.x * 256 + threadIdx.x;   // 0 .. 524287
  const int row = gt >> 5;                          // 0 .. 16383
  const int seg = gt & 31;                          // float4 slot in row
  const bool isx = row < NPTS;
  const float* src        = isx ? (x  + (size_t)row * DIM) : (y  + (size_t)(row - NPTS) * DIM);
  unsigned short* dst     = isx ? (Xc + (size_t)row * KC)  : (Yc + (size_t)(row - NPTS) * KC);

  f32x4 v = *reinterpret_cast<const f32x4*>(src + seg * 4);
  float sq = v[0]*v[0] + v[1]*v[1] + v[2]*v[2] + v[3]*v[3];
  #pragma unroll
  for (int m = 1; m <= 16; m <<= 1) sq += __shfl_xor(sq, m);   // 32-lane segmented reduce
  if (seg == 0) { if (isx) x2[row] = sq; else y2[row - NPTS] = sq; }

  const float scale = isx ? -2.0f : 1.0f;           // fold the -2 into X (exact)
  unsigned short hb[4];
  #pragma unroll
  for (int i = 0; i < 4; ++i) {
    __hip_bfloat16 h = __float2bfloat16(scale * v[i]);
    hb[i] = __builtin_bit_cast(unsigned short, h);
  }
  *reinterpret_cast<ushort4*>(dst + seg * 4) = make_ushort4(hb[0], hb[1], hb[2], hb[3]);

  if (gt < NPTS)          minx[gt]        = 0x7F800000u;   // +inf
  else if (gt < 2 * NPTS) miny[gt - NPTS] = 0x7F800000u;
}

// ---------------------------------------------------------------- gemm ----
// 512 threads / 8 waves (2x4); per wave 128x64 via acc[8][4] of
// mfma_f32_16x16x32_bf16. Per block: A resident (both K-chunks), 4 tiles:
//   t: { stage B1<-(t,k1) || phase0(A0,B0); sync;
//        stage B0<-(t+1,k0) || phase1(A1,B1); sync; epilogue; sync; atomics }
__global__ __launch_bounds__(512, 2) void chamfer_gemm(
    const unsigned short* __restrict__ Xc, const unsigned short* __restrict__ Yc,
    const float* __restrict__ x2, const float* __restrict__ y2,
    unsigned int* __restrict__ minx, unsigned int* __restrict__ miny)
{
  __shared__ alignas(16) unsigned short As[2][256 * 64];   // 64 KB, resident
  __shared__ alignas(16) unsigned short Bs[2][256 * 64];   // 64 KB, k0/k1 dbuf
  __shared__ float colminLDS[2 * 256];                     // dedicated scratch
  __shared__ float rowminLDS[4 * 256];

  const int tid  = threadIdx.x;
  const int lane = tid & 63;
  const int w    = tid >> 6;        // 0..7
  const int wr   = w >> 2;          // 0..1  (rows: wr*128)
  const int wc   = w & 3;           // 0..3  (cols: wc*64)

  // XCD map: xcd = b&7 -> bi in [xcd*4, xcd*4+4); local = b>>3 (0..31):
  // bi = xcd*4 + (local>>3), bj0 = (local&7)*4; block owns bj0..bj0+3.
  const int b     = blockIdx.x;
  const int local = b >> 3;
  const int bi    = (b & 7) * 4 + (local >> 3);
  const int bj0   = (local & 7) * 4;

  // staging geometry (proven): LDS byte = row*128 + slot*16 (linear),
  // slot = tid&7, row = l*64 + (tid>>3); source pre-swizzled:
  // kgroup = slot ^ (row&7).
  const int r64  = tid >> 3;               // 0..63
  const int kgrp = (tid & 7) ^ (r64 & 7);
  const unsigned short* Abase = Xc + (size_t)(bi * 256 + r64) * KC + kgrp * 8;
  const int wofs = w * 1024;               // wave-uniform LDS base offset

  auto STAGE_A = [&](int kt) {
    const unsigned short* Asrc = Abase + kt * 64;
    char* Ad = (char*)&As[kt][0] + wofs;
    #pragma unroll
    for (int l = 0; l < 4; ++l)
      gload_lds16(Asrc + (size_t)l * 64 * KC, Ad + l * 8192);
  };
  auto STAGE_B = [&](int buf, int t, int kt) {
    const unsigned short* Bsrc = Yc + (size_t)((bj0 + t) * 256 + r64) * KC + kgrp * 8 + kt * 64;
    char* Bd = (char*)&Bs[buf][0] + wofs;
    #pragma unroll
    for (int l = 0; l < 4; ++l)
      gload_lds16(Bsrc + (size_t)l * 64 * KC, Bd + l * 8192);
  };

  // ---- prologue: A (both chunks) + B(0,k0); x2 hoisted; y2(t=0) ----
  STAGE_A(0);
  STAGE_A(1);
  STAGE_B(0, 0, 0);

  f32x4 xv[8];
  #pragma unroll
  for (int mi = 0; mi < 8; ++mi)
    xv[mi] = *reinterpret_cast<const f32x4*>(x2 + bi * 256 + wr * 128 + mi * 16 + ((lane >> 4) << 2));
  float yv[4];
  #pragma unroll
  for (int ni = 0; ni < 4; ++ni)
    yv[ni] = y2[bj0 * 256 + wc * 64 + ni * 16 + (lane & 15)];

  float rowrun0 = 3.0e38f, rowrun1 = 3.0e38f;   // running minx (tid>=256 uses rowrun0)

  __syncthreads();   // drains vmcnt: A0, A1, B(0,k0) staged

  for (int t = 0; t < 4; ++t) {
    // acc init = x2[row] + y2[col]  ->  accumulator IS the distance
    f32x4 acc[8][4];
    #pragma unroll
    for (int mi = 0; mi < 8; ++mi)
      #pragma unroll
      for (int ni = 0; ni < 4; ++ni)
        #pragma unroll
        for (int r = 0; r < 4; ++r)
          acc[mi][ni][r] = xv[mi][r] + yv[ni];

    // prefetch next tile's y2 (consumed next iteration)
    float yvn[4];
    if (t < 3) {
      #pragma unroll
      for (int ni = 0; ni < 4; ++ni)
        yvn[ni] = y2[(bj0 + t + 1) * 256 + wc * 64 + ni * 16 + (lane & 15)];
    }

    #pragma unroll
    for (int kt = 0; kt < 2; ++kt) {
      // stage the other buffer while computing this one
      if (kt == 0)      STAGE_B(1, t, 1);
      else if (t < 3)   STAGE_B(0, t + 1, 0);

      const char* Ab = (const char*)&As[kt][0];
      const char* Bb = (const char*)&Bs[kt][0];

      bf16x8 bfr[4][2];
      #pragma unroll
      for (int ni = 0; ni < 4; ++ni) {
        const int col = wc * 64 + ni * 16 + (lane & 15);
        const int swz = (col & 7) << 4;
        #pragma unroll
        for (int ks = 0; ks < 2; ++ks) {
          const int ofs = (ks * 64 + ((lane >> 4) << 4)) ^ swz;
          bfr[ni][ks] = *reinterpret_cast<const bf16x8*>(Bb + col * 128 + ofs);
        }
      }
      #pragma unroll
      for (int mi = 0; mi < 8; ++mi) {
        const int rowl = wr * 128 + mi * 16 + (lane & 15);
        const int swz  = (rowl & 7) << 4;
        const bf16x8 a0 = *reinterpret_cast<const bf16x8*>(Ab + rowl * 128 + ((  0 + ((lane >> 4) << 4)) ^ swz));
        const bf16x8 a1 = *reinterpret_cast<const bf16x8*>(Ab + rowl * 128 + (( 64 + ((lane >> 4) << 4)) ^ swz));
        #pragma unroll
        for (int ni = 0; ni < 4; ++ni) {
          acc[mi][ni] = __builtin_amdgcn_mfma_f32_16x16x32_bf16(a0, bfr[ni][0], acc[mi][ni], 0, 0, 0);
          acc[mi][ni] = __builtin_amdgcn_mfma_f32_16x16x32_bf16(a1, bfr[ni][1], acc[mi][ni], 0, 0, 0);
        }
      }
      __syncthreads();   // staged loads landed; buffer reads done before reuse
    }

    // ---- epilogue (tile t): pure min reductions (acc already = dist) ----
    float cm[4];
    #pragma unroll
    for (int ni = 0; ni < 4; ++ni) {
      float m = 3.0e38f;
      #pragma unroll
      for (int mi = 0; mi < 8; ++mi)
        #pragma unroll
        for (int r = 0; r < 4; ++r)
          m = fminf(m, acc[mi][ni][r]);
      cm[ni] = m;
    }
    {
      const bool hb0 = (lane & 16) != 0;
      float s0 = hb0 ? cm[0] : cm[2];
      float s1 = hb0 ? cm[1] : cm[3];
      float r0 = __shfl_xor(s0, 16);
      float r1 = __shfl_xor(s1, 16);
      float t0 = fminf(hb0 ? cm[2] : cm[0], r0);
      float t1 = fminf(hb0 ? cm[3] : cm[1], r1);
      const bool hb1 = (lane & 32) != 0;
      float s  = hb1 ? t0 : t1;
      float rr = __shfl_xor(s, 32);
      float cfin = fminf(hb1 ? t1 : t0, rr);
      const int ni = (hb0 ? 2 : 0) + (hb1 ? 1 : 0);    // bitrev2(lane>>4)
      colminLDS[wr * 256 + wc * 64 + ni * 16 + (lane & 15)] = cfin;
    }

    float rm[32];
    #pragma unroll
    for (int mi = 0; mi < 8; ++mi)
      #pragma unroll
      for (int r = 0; r < 4; ++r)
        rm[mi * 4 + r] = fminf(fminf(acc[mi][0][r], acc[mi][1][r]),
                               fminf(acc[mi][2][r], acc[mi][3][r]));
    #pragma unroll
    for (int b2 = 0; b2 < 4; ++b2) {
      const int  half = 16 >> b2;
      const bool up   = (lane >> b2) & 1;
      #pragma unroll
      for (int i = 0; i < half; ++i) {
        float snd = up ? rm[i] : rm[i + half];
        float rcv = __shfl_xor(snd, 1 << b2);
        rm[i] = fminf(up ? rm[i + half] : rm[i], rcv);
      }
    }
    {
      // surviving rm[e], e in {0,1}: idx = l0<<4 | l1<<3 | l2<<2 | l3<<1 | e
      const int base = ((lane & 1) << 4) | ((lane & 2) << 2) | (lane & 4) | ((lane & 8) >> 2);
      #pragma unroll
      for (int e = 0; e < 2; ++e) {
        const int idx = base | e;
        const int row_local = wr * 128 + (idx >> 2) * 16 + ((lane >> 4) << 2) + (idx & 3);
        rowminLDS[wc * 256 + row_local] = rm[e];
      }
    }
    __syncthreads();   // scratch visible

    // per-tile miny atomic (bj changes per tile); minx deferred via register
    if (tid < 256) {
      float c = fminf(colminLDS[tid], colminLDS[256 + tid]);
      atomicMin(&miny[(bj0 + t) * 256 + tid], __float_as_uint(fmaxf(c, 0.f)));
    } else {
      const int r = tid - 256;
      float v = fminf(fminf(rowminLDS[r], rowminLDS[256 + r]),
                      fminf(rowminLDS[512 + r], rowminLDS[768 + r]));
      rowrun0 = fminf(rowrun0, v);
    }
    (void)rowrun1;

    #pragma unroll
    for (int ni = 0; ni < 4; ++ni) yv[ni] = yvn[ni];
    // no extra sync: next tile's scratch WRITE is 2 barriers away; next
    // STAGE_B(1) targets Bs[1], whose last reads preceded the phase-1 sync.
  }

  // one minx atomic per row per block (min over the block's 4 tiles)
  if (tid >= 256)
    atomicMin(&minx[bi * 256 + (tid - 256)], __float_as_uint(fmaxf(rowrun0, 0.f)));
}

// ------------------------------------------------------------- finalize ----
__global__ __launch_bounds__(256) void finalize_kernel(
    const unsigned int* __restrict__ minx, const unsigned int* __restrict__ miny,
    float* __restrict__ out)
{
  // all stored patterns are non-negative floats; reinterpret directly
  const f32x4* mx = (const f32x4*)minx;
  const f32x4* my = (const f32x4*)miny;
  float s = 0.f;
  for (int i = threadIdx.x; i < NPTS / 4; i += 256) {
    f32x4 a = mx[i], b = my[i];
    s += (a[0] + a[1] + a[2] + a[3]) + (b[0] + b[1] + b[2] + b[3]);
  }
  #pragma unroll
  for (int m = 32; m >= 1; m >>= 1) s += __shfl_xor(s, m);
  __shared__ float partial[4];
  if ((threadIdx.x & 63) == 0) partial[threadIdx.x >> 6] = s;
  __syncthreads();
  if (threadIdx.x == 0)
    out[0] = (partial[0] + partial[1] + partial[2] + partial[3]) * (1.0f / (float)NPTS);
}

// ---------------------------------------------------------------- launch ----
extern "C" void kernel_launch(void* const* d_in, const int* in_sizes, int n_in,
                              void* d_out, int out_size, void* d_ws, size_t ws_size,
                              hipStream_t stream) {
  (void)in_sizes; (void)n_in; (void)out_size; (void)ws_size;
  const float* x = (const float*)d_in[0];
  const float* y = (const float*)d_in[1];
  char* ws = (char*)d_ws;

  // ws layout: Xc 2MB | Yc 2MB | x2 32KB | y2 32KB | minx 32KB | miny 32KB
  unsigned short* Xc  = (unsigned short*)(ws);
  unsigned short* Yc  = (unsigned short*)(ws + 2097152);
  float*          x2  = (float*)(ws + 4194304);
  float*          y2  = (float*)(ws + 4227072);
  unsigned int*   mnx = (unsigned int*)(ws + 4259840);
  unsigned int*   mny = (unsigned int*)(ws + 4292608);
  float*          out = (float*)d_out;

  prep_kernel<<<2048, 256, 0, stream>>>(x, y, Xc, Yc, x2, y2, mnx, mny);
  chamfer_gemm<<<256, 512, 0, stream>>>(Xc, Yc, x2, y2, mnx, mny);
  finalize_kernel<<<1, 256, 0, stream>>>(mnx, mny, out);
}